// Round 1
// baseline (834.157 us; speedup 1.0000x reference)
//
#include <hip/hip_runtime.h>
#include <hip/hip_bf16.h>
#include <math.h>

// Problem constants (verified against in_sizes at launch where possible)
#define HH 8
#define DD 16
#define HD 128  // H*D

// One wave (64 lanes) per edge. Lane l covers head h = l>>3, dims d = 2*(l&7), 2*(l&7)+1.
__global__ void __launch_bounds__(256) edge_kernel(
    const float* __restrict__ node,   // [N,H,D]
    const float* __restrict__ eft,    // [E,H,D]
    const int*   __restrict__ dst,    // [E]
    float*       __restrict__ nft,    // [N,H,D] workspace, pre-zeroed
    float*       __restrict__ a_out,  // [E,H]
    int E)
{
    int wave = (int)((blockIdx.x * blockDim.x + threadIdx.x) >> 6);
    int lane = threadIdx.x & 63;
    if (wave >= E) return;
    const int e = wave;
    const int dn = dst[e];  // wave-uniform -> scalar load

    const float2* eftp  = (const float2*)(eft  + (size_t)e  * HD);
    const float2* nodep = (const float2*)(node + (size_t)dn * HD);
    float2 ev = eftp[lane];
    float2 nv = nodep[lane];

    // per-head dot product over D=16 (8 lanes x 2 elems)
    float p = ev.x * nv.x + ev.y * nv.y;
    p += __shfl_xor(p, 1);
    p += __shfl_xor(p, 2);
    p += __shfl_xor(p, 4);
    // p = sim[e][h] replicated across the 8 lanes of head group h

    // softmax over the 8 heads (butterfly across head groups)
    float m = p;
    m = fmaxf(m, __shfl_xor(m, 8));
    m = fmaxf(m, __shfl_xor(m, 16));
    m = fmaxf(m, __shfl_xor(m, 32));
    float ex = __expf(p - m);
    float s = ex;
    s += __shfl_xor(s, 8);
    s += __shfl_xor(s, 16);
    s += __shfl_xor(s, 32);
    float a = ex / s;

    if ((lane & 7) == 0)
        a_out[(size_t)e * HH + (lane >> 3)] = a;

    // scatter-sum eft * a into nft[dst]
    float* dp = nft + (size_t)dn * HD + lane * 2;
    atomicAdd(dp,     ev.x * a);
    atomicAdd(dp + 1, ev.y * a);
}

// One thread per (t, d): gather nft[target_idx[t]], L2-normalize over heads.
__global__ void __launch_bounds__(256) target_kernel(
    const float* __restrict__ nft,        // [N,H,D]
    const int*   __restrict__ target_idx, // [T]
    float*       __restrict__ out,        // [T,H,D]
    int T)
{
    int idx = blockIdx.x * blockDim.x + threadIdx.x;
    if (idx >= T * DD) return;
    int t = idx >> 4;        // /16
    int d = idx & (DD - 1);
    int n = target_idx[t];
    const float* p = nft + (size_t)n * HD + d;
    float x[HH];
    float ss = 0.0f;
#pragma unroll
    for (int h = 0; h < HH; h++) {
        x[h] = p[h * DD] + 1e-15f;
        ss += x[h] * x[h];
    }
    float inv = 1.0f / fmaxf(sqrtf(ss), 1e-12f);
    float* o = out + (size_t)t * HD + d;
#pragma unroll
    for (int h = 0; h < HH; h++)
        o[h * DD] = x[h] * inv;
}

extern "C" void kernel_launch(void* const* d_in, const int* in_sizes, int n_in,
                              void* d_out, int out_size, void* d_ws, size_t ws_size,
                              hipStream_t stream)
{
    const float* node = (const float*)d_in[0];  // [N,H,D]
    const float* eft  = (const float*)d_in[1];  // [E,H,D]
    const int*   dst  = (const int*)d_in[2];    // [E]
    const int*   tidx = (const int*)d_in[3];    // [T]

    const int N = in_sizes[0] / HD;
    const int E = in_sizes[2];
    const int T = in_sizes[3];

    float* out   = (float*)d_out;                 // [T,H,D] first
    float* a_out = out + (size_t)T * HD;          // then [E,H]
    float* nft   = (float*)d_ws;                  // [N,H,D] scratch

    // zero the scatter accumulator (d_ws is poisoned 0xAA before every launch)
    hipMemsetAsync(nft, 0, (size_t)N * HD * sizeof(float), stream);

    // edge pass: one wave per edge, 4 edges per 256-thread block
    {
        int waves_per_block = 256 / 64;
        int blocks = (E + waves_per_block - 1) / waves_per_block;
        edge_kernel<<<blocks, 256, 0, stream>>>(node, eft, dst, nft, a_out, E);
    }

    // target pass: one thread per (t,d)
    {
        int total = T * DD;
        int blocks = (total + 255) / 256;
        target_kernel<<<blocks, 256, 0, stream>>>(nft, tidx, out, T);
    }
}

// Round 2
// 518.809 us; speedup vs baseline: 1.6078x; 1.6078x over previous
//
#include <hip/hip_runtime.h>
#include <hip/hip_bf16.h>
#include <math.h>

// Problem constants
#define HH 8
#define DD 16
#define HD 128  // H*D

// One wave per target: mark the node and zero its nft row.
// Duplicate targets race benignly (same values written).
__global__ void __launch_bounds__(256) mark_zero_kernel(
    const int* __restrict__ tidx,   // [T]
    unsigned char* __restrict__ mark, // [N]
    float* __restrict__ nft,        // [N,H,D]
    int T)
{
    int wave = (int)((blockIdx.x * blockDim.x + threadIdx.x) >> 6);
    int lane = threadIdx.x & 63;
    if (wave >= T) return;
    int n = tidx[wave];
    if (lane == 0) mark[n] = 1;
    float2* p = (float2*)(nft + (size_t)n * HD);
    p[lane] = make_float2(0.0f, 0.0f);
}

// One wave (64 lanes) per edge. Lane l covers head h = l>>3, dims 2*(l&7), 2*(l&7)+1.
__global__ void __launch_bounds__(256) edge_kernel(
    const float* __restrict__ node,   // [N,H,D]
    const float* __restrict__ eft,    // [E,H,D]
    const int*   __restrict__ dst,    // [E]
    const unsigned char* __restrict__ mark, // [N]
    float*       __restrict__ nft,    // [N,H,D] zeroed at marked rows
    float*       __restrict__ a_out,  // [E,H]
    int E)
{
    int wave = (int)((blockIdx.x * blockDim.x + threadIdx.x) >> 6);
    int lane = threadIdx.x & 63;
    if (wave >= E) return;
    const int e = wave;
    const int dn = dst[e];  // wave-uniform

    const float2* eftp  = (const float2*)(eft  + (size_t)e  * HD);
    const float2* nodep = (const float2*)(node + (size_t)dn * HD);
    float2 ev = eftp[lane];
    float2 nv = nodep[lane];

    // per-head dot over D=16 (8 lanes x 2 elems)
    float p = ev.x * nv.x + ev.y * nv.y;
    p += __shfl_xor(p, 1);
    p += __shfl_xor(p, 2);
    p += __shfl_xor(p, 4);

    // softmax over the 8 heads (butterfly across head groups)
    float m = p;
    m = fmaxf(m, __shfl_xor(m, 8));
    m = fmaxf(m, __shfl_xor(m, 16));
    m = fmaxf(m, __shfl_xor(m, 32));
    float ex = __expf(p - m);
    float s = ex;
    s += __shfl_xor(s, 8);
    s += __shfl_xor(s, 16);
    s += __shfl_xor(s, 32);
    float a = ex / s;

    // a_out[e*8 + h] from lanes 0,8,...,56 -> one contiguous 32B transaction
    if ((lane & 7) == 0)
        a_out[(size_t)e * HH + (lane >> 3)] = a;

    // scatter only into rows that will actually be read (target nodes)
    if (mark[dn]) {   // wave-uniform branch, no divergence
        float* dp = nft + (size_t)dn * HD + lane * 2;
        atomicAdd(dp,     ev.x * a);
        atomicAdd(dp + 1, ev.y * a);
    }
}

// One thread per (t, d): gather nft[target_idx[t]], L2-normalize over heads.
__global__ void __launch_bounds__(256) target_kernel(
    const float* __restrict__ nft,        // [N,H,D]
    const int*   __restrict__ target_idx, // [T]
    float*       __restrict__ out,        // [T,H,D]
    int T)
{
    int idx = blockIdx.x * blockDim.x + threadIdx.x;
    if (idx >= T * DD) return;
    int t = idx >> 4;
    int d = idx & (DD - 1);
    int n = target_idx[t];
    const float* p = nft + (size_t)n * HD + d;
    float x[HH];
    float ss = 0.0f;
#pragma unroll
    for (int h = 0; h < HH; h++) {
        x[h] = p[h * DD] + 1e-15f;
        ss += x[h] * x[h];
    }
    float inv = 1.0f / fmaxf(sqrtf(ss), 1e-12f);
    float* o = out + (size_t)t * HD + d;
#pragma unroll
    for (int h = 0; h < HH; h++)
        o[h * DD] = x[h] * inv;
}

extern "C" void kernel_launch(void* const* d_in, const int* in_sizes, int n_in,
                              void* d_out, int out_size, void* d_ws, size_t ws_size,
                              hipStream_t stream)
{
    const float* node = (const float*)d_in[0];  // [N,H,D]
    const float* eft  = (const float*)d_in[1];  // [E,H,D]
    const int*   dst  = (const int*)d_in[2];    // [E]
    const int*   tidx = (const int*)d_in[3];    // [T]

    const int N = in_sizes[0] / HD;
    const int E = in_sizes[2];
    const int T = in_sizes[3];

    float* out   = (float*)d_out;                 // [T,H,D] first
    float* a_out = out + (size_t)T * HD;          // then [E,H]
    float* nft   = (float*)d_ws;                  // [N,H,D] scratch (only marked rows used)

    // mask lives in the head of the out region (T*HD floats = 10.2 MB >> N bytes);
    // target_kernel fully overwrites it afterwards.
    unsigned char* mark = (unsigned char*)d_out;

    // clear mask (100 KB)
    hipMemsetAsync(mark, 0, (size_t)N, stream);

    // mark targets + zero only their accumulator rows (1 wave / target)
    {
        int waves_per_block = 256 / 64;
        int blocks = (T + waves_per_block - 1) / waves_per_block;
        mark_zero_kernel<<<blocks, 256, 0, stream>>>(tidx, mark, nft, T);
    }

    // edge pass: one wave per edge
    {
        int waves_per_block = 256 / 64;
        int blocks = (E + waves_per_block - 1) / waves_per_block;
        edge_kernel<<<blocks, 256, 0, stream>>>(node, eft, dst, mark, nft, a_out, E);
    }

    // target pass: one thread per (t,d); overwrites the mask region of d_out
    {
        int total = T * DD;
        int blocks = (total + 255) / 256;
        target_kernel<<<blocks, 256, 0, stream>>>(nft, tidx, out, T);
    }
}